// Round 14
// baseline (294.237 us; speedup 1.0000x reference)
//
#include <hip/hip_runtime.h>

#define B_ 2
#define N_ 16384
#define M_ 4096
#define D_ 128

typedef __attribute__((ext_vector_type(8))) short s8;     // 8 bf16 (4 VGPRs)
typedef __attribute__((ext_vector_type(4))) float f4;     // MFMA C/D + float4 loads
typedef __attribute__((ext_vector_type(16))) float f16v;  // 32x32 MFMA C/D
typedef __attribute__((ext_vector_type(4))) unsigned short us4;
typedef unsigned short u16;

__device__ __forceinline__ u16 f2b(float f) {   // RNE float->bf16
  unsigned int x = __float_as_uint(f);
  unsigned int r = x + 0x7fffu + ((x >> 16) & 1u);
  return (u16)(r >> 16);
}
__device__ __forceinline__ s8 ld8(const u16* p) {
  return *reinterpret_cast<const s8*>(p);
}
__device__ __forceinline__ s8 ldcvt8(const float* p) {
  f4 x = *reinterpret_cast<const f4*>(p);
  f4 y = *reinterpret_cast<const f4*>(p + 4);
  s8 r;
  r[0] = (short)f2b(x[0]); r[1] = (short)f2b(x[1]);
  r[2] = (short)f2b(x[2]); r[3] = (short)f2b(x[3]);
  r[4] = (short)f2b(y[0]); r[5] = (short)f2b(y[1]);
  r[6] = (short)f2b(y[2]); r[7] = (short)f2b(y[3]);
  return r;
}
__device__ __forceinline__ f4 mfma16(s8 a, s8 b, f4 c) {
  return __builtin_amdgcn_mfma_f32_16x16x32_bf16(a, b, c, 0, 0, 0);
}
__device__ __forceinline__ f16v mfma32(s8 a, s8 b, f16v c) {
  return __builtin_amdgcn_mfma_f32_32x32x16_bf16(a, b, c, 0, 0, 0);
}
// XOR-swizzled LDS offset for 256B rows. off = byte offset in row.
__device__ __forceinline__ int swz(int row, int off) {
  return (row << 8) + ((((off >> 4) ^ (row & 15)) << 4) | (off & 15));
}
// scale * log2(e): exp(s/sqrt(128)) == exp2(s * CS)
#define CS 0.1275174365f

// LDS-visibility-only barrier: drains ds ops (lgkm) but NOT vmem (vmcnt) —
// v10 verified correctness + parity vs __syncthreads. No sched_barrier pins.
__device__ __forceinline__ void lds_barrier() {
  asm volatile("s_waitcnt lgkmcnt(0)" ::: "memory");
  __builtin_amdgcn_s_barrier();
}

// Transpose seven 128x128 f32 weight matrices into ws as bf16 Wt[n][k].
// 112 blocks: block (mat, part) writes output slice part*1024..+1023 coalesced.
__global__ __launch_bounds__(256) void wtrans(
    const float* a0, const float* a1, const float* a2, const float* a3,
    const float* a4, const float* a5, const float* a6, u16* dst) {
  const int mat = blockIdx.x >> 4, part = blockIdx.x & 15;
  const float* s;
  switch (mat) {
    case 0: s = a0; break; case 1: s = a1; break; case 2: s = a2; break;
    case 3: s = a3; break; case 4: s = a4; break; case 5: s = a5; break;
    default: s = a6; break;
  }
  u16* d = dst + mat * 16384 + part * 1024;
  const int o0 = part * 1024;
  for (int i = threadIdx.x; i < 1024; i += 256) {
    const int o = o0 + i;
    const int c = o >> 7, r = o & 127;
    d[i] = f2b(s[r * 128 + c]);
  }
}

// Fused MLPs, one launch (r12 bodies unchanged):
//  blocks [0,256):   Q = alpha-MLP(v_feat)            -> qbuf
//  blocks [256,768): kpv = beta+delta MLPs, vt = omega -> kpvb / vtb
__global__ __launch_bounds__(256) void mlps(
    const float* __restrict__ vfeat,
    const u16* __restrict__ aW1t, const float* __restrict__ ab1,
    const u16* __restrict__ aW2t, const float* __restrict__ ab2,
    u16* __restrict__ qbuf,
    const float* __restrict__ pf, const float* __restrict__ pxyz,
    const float* __restrict__ vxyz,
    const u16* __restrict__ bW1t, const float* __restrict__ bb1,
    const u16* __restrict__ bW2t, const float* __restrict__ bb2,
    const float* __restrict__ dW1, const float* __restrict__ db1,
    const u16* __restrict__ dW2t, const float* __restrict__ db2,
    const u16* __restrict__ oW1t, const float* __restrict__ ob1,
    const u16* __restrict__ oW2t, const float* __restrict__ ob2,
    u16* __restrict__ kpv_out, u16* __restrict__ vt_out) {
  __shared__ u16 H1[64][136];
  __shared__ u16 H2[64][136];
  __shared__ u16 H3[64][136];
  const int tid = threadIdx.x;
  const int wave = tid >> 6, lane = tid & 63;
  const int c16 = lane & 15, quad = lane >> 4;

  if (blockIdx.x < 256) {
    // ---------------- Q path: 32 rows/block ----------------
    const int rowg = wave & 1, nsh = wave >> 1;
    const long row0 = (long)blockIdx.x * 32 + rowg * 16;
    s8 a[4];
    {
      const float* xr = vfeat + (row0 + c16) * D_ + quad * 8;
      #pragma unroll
      for (int kk = 0; kk < 4; kk++) a[kk] = ldcvt8(xr + kk * 32);
    }
    #pragma unroll
    for (int ns = 0; ns < 4; ns++) {
      f4 acc = {0.f, 0.f, 0.f, 0.f};
      const int c = (nsh * 4 + ns) * 16 + c16;
      const u16* wr = aW1t + (long)c * 128 + quad * 8;
      #pragma unroll
      for (int kk = 0; kk < 4; kk++) acc = mfma16(a[kk], ld8(wr + kk * 32), acc);
      const float bias = ab1[c];
      #pragma unroll
      for (int r = 0; r < 4; r++) {
        float v = acc[r] + bias;
        H1[rowg * 16 + quad * 4 + r][c] = f2b(v > 0.f ? v : 0.f);
      }
    }
    __syncthreads();
    s8 a2[4];
    #pragma unroll
    for (int kk = 0; kk < 4; kk++)
      a2[kk] = *reinterpret_cast<const s8*>(&H1[rowg * 16 + c16][kk * 32 + quad * 8]);
    #pragma unroll
    for (int ns = 0; ns < 4; ns++) {
      f4 acc = {0.f, 0.f, 0.f, 0.f};
      const int c = (nsh * 4 + ns) * 16 + c16;
      const u16* wr = aW2t + (long)c * 128 + quad * 8;
      #pragma unroll
      for (int kk = 0; kk < 4; kk++) acc = mfma16(a2[kk], ld8(wr + kk * 32), acc);
      const float bias = ab2[c];
      #pragma unroll
      for (int r = 0; r < 4; r++)
        qbuf[(row0 + quad * 4 + r) * D_ + c] = f2b(acc[r] + bias);
    }
    return;
  }
  // ---------------- kpv + vt path: 64 rows/block ----------------
  const int bx = blockIdx.x - 256;
  const long row0 = (long)bx * 64 + wave * 16;
  s8 a[4];
  {
    const float* xr = pf + (row0 + c16) * D_ + quad * 8;
    #pragma unroll
    for (int kk = 0; kk < 4; kk++) a[kk] = ldcvt8(xr + kk * 32);
  }
  #pragma unroll
  for (int ns = 0; ns < 8; ns++) {
    f4 accb = {0.f, 0.f, 0.f, 0.f}, acco = {0.f, 0.f, 0.f, 0.f};
    const int c = ns * 16 + c16;
    const u16* wrb = bW1t + (long)c * 128 + quad * 8;
    const u16* wro = oW1t + (long)c * 128 + quad * 8;
    #pragma unroll
    for (int kk = 0; kk < 4; kk++) {
      accb = mfma16(a[kk], ld8(wrb + kk * 32), accb);
      acco = mfma16(a[kk], ld8(wro + kk * 32), acco);
    }
    const float biasb = bb1[c], biaso = ob1[c];
    #pragma unroll
    for (int r = 0; r < 4; r++) {
      float vb = accb[r] + biasb;
      float vo = acco[r] + biaso;
      H1[wave * 16 + quad * 4 + r][c] = f2b(vb > 0.f ? vb : 0.f);
      H3[wave * 16 + quad * 4 + r][c] = f2b(vo > 0.f ? vo : 0.f);
    }
  }
  {
    const long bat = ((long)bx * 64) / N_;
    const float vx0 = vxyz[bat * 3 + 0];
    const float vx1 = vxyz[bat * 3 + 1];
    const float vx2 = vxyz[bat * 3 + 2];
    for (int i = 0; i < 32; i++) {
      const int e = lane + 64 * i;
      const int rr = e >> 7, cc = e & 127;
      const long gr = row0 + rr;
      const float d0 = fabsf(pxyz[gr * 3 + 0] - vx0);
      const float d1 = fabsf(pxyz[gr * 3 + 1] - vx1);
      const float d2 = fabsf(pxyz[gr * 3 + 2] - vx2);
      float h = d0 * dW1[cc] + d1 * dW1[128 + cc] + d2 * dW1[256 + cc] + db1[cc];
      H2[wave * 16 + rr][cc] = f2b(h > 0.f ? h : 0.f);
    }
  }
  __syncthreads();                               // single fence: writes -> reads
  s8 ab[4], ad[4], ao[4];
  #pragma unroll
  for (int kk = 0; kk < 4; kk++) {
    ab[kk] = *reinterpret_cast<const s8*>(&H1[wave * 16 + c16][kk * 32 + quad * 8]);
    ad[kk] = *reinterpret_cast<const s8*>(&H2[wave * 16 + c16][kk * 32 + quad * 8]);
    ao[kk] = *reinterpret_cast<const s8*>(&H3[wave * 16 + c16][kk * 32 + quad * 8]);
  }
  #pragma unroll
  for (int ns = 0; ns < 8; ns++) {
    const int c = ns * 16 + c16;
    f4 acck = {0.f, 0.f, 0.f, 0.f};              // kpv = beta-L2 + delta-L2
    f4 accv = {0.f, 0.f, 0.f, 0.f};              // vt = omega-L2
    const u16* wrb = bW2t + (long)c * 128 + quad * 8;
    const u16* wrd = dW2t + (long)c * 128 + quad * 8;
    const u16* wro = oW2t + (long)c * 128 + quad * 8;
    #pragma unroll
    for (int kk = 0; kk < 4; kk++) {
      acck = mfma16(ab[kk], ld8(wrb + kk * 32), acck);
      acck = mfma16(ad[kk], ld8(wrd + kk * 32), acck);
      accv = mfma16(ao[kk], ld8(wro + kk * 32), accv);
    }
    const float biask = bb2[c] + db2[c];
    const float biasv = ob2[c];
    #pragma unroll
    for (int r = 0; r < 4; r++)
      kpv_out[(row0 + quad * 4 + r) * D_ + c] = f2b(acck[r] + biask);
    {
      const long g = row0 + quad * 4;
      const long bb = g >> 14;
      const long n = g & (N_ - 1);
      us4 pk;
      #pragma unroll
      for (int r = 0; r < 4; r++) pk[r] = f2b(accv[r] + biasv);
      *reinterpret_cast<us4*>(vt_out + bb * (long)128 * N_ + (long)c * N_ + n) = pk;
    }
  }
}

// Pass 1 v5 = v4b (r13 verified: out of top-5, no spill) with the ending
// changed: the four m-split partials are atomicAdd'ed into invb (zeroed by
// hipMemsetAsync) instead of staged in a sums buffer. This removes the
// recip_k launch (attn computes -log2f in its prologue) and the
// sums<->partb alias. Atomics: 8 f32 adds per wave, 4 waves/n-range —
// negligible contention; f32 sum reorder is sub-ulp vs tolerance.
__global__ __launch_bounds__(512, 2) void colsum_v5(const u16* __restrict__ q,
    const u16* __restrict__ kpv, float* __restrict__ invb) {
  __shared__ char LQ[2][32768];                  // 2 x (128 m x 128 k bf16), swz
  const int tid = threadIdx.x;
  const int wave = tid >> 6, lane = tid & 63;
  const int c16 = lane & 15, quad = lane >> 4;
  const int mh = blockIdx.x & 3;                 // m-split
  const int nblk = (blockIdx.x >> 2) & 63;       // 256-n block
  const int b = blockIdx.x >> 8;
  const int nb = nblk * 256 + wave * 32;         // wave's 32 n rows
  const int rsub = lane >> 4, ch = lane & 15;

  s8 ak[2][4];                                   // two 16-n A-tiles
  #pragma unroll
  for (int t = 0; t < 2; t++) {
    const u16* kr = kpv + ((long)b * N_ + nb + t * 16 + c16) * D_ + quad * 8;
    #pragma unroll
    for (int kk = 0; kk < 4; kk++) ak[t][kk] = ld8(kr + kk * 32);
  }
  f4 sum0 = {0.f, 0.f, 0.f, 0.f};
  f4 sum1 = {0.f, 0.f, 0.f, 0.f};
  const u16* qb = q + (long)b * M_ * D_ + (long)mh * (M_ / 4) * D_;

  // prologue: stage 0 (load + write)
  {
    s8 t4[4];
    #pragma unroll
    for (int i = 0; i < 4; i++)
      t4[i] = ld8(qb + (long)(wave * 16 + i * 4 + rsub) * D_ + ch * 8);
    #pragma unroll
    for (int i = 0; i < 4; i++)
      *reinterpret_cast<s8*>(LQ[0] + swz(wave * 16 + i * 4 + rsub, ch * 16)) = t4[i];
  }

  for (int s = 0; s < 8; s++) {                  // 8 stages x 128 m = M/4
    lds_barrier();                               // W(s) visible; R(s-1) done
    if (s < 7) {                                 // stage s+1: load+write now
      s8 t4[4];                                  // (short liveness: no spill)
      const int m1 = (s + 1) * 128;
      #pragma unroll
      for (int i = 0; i < 4; i++)
        t4[i] = ld8(qb + (long)(m1 + wave * 16 + i * 4 + rsub) * D_ + ch * 8);
      #pragma unroll
      for (int i = 0; i < 4; i++)
        *reinterpret_cast<s8*>(LQ[(s + 1) & 1]
            + swz(wave * 16 + i * 4 + rsub, ch * 16)) = t4[i];
    }
    const char* lq = LQ[s & 1];
    #pragma unroll
    for (int ms = 0; ms < 8; ms++) {
      f4 st0 = {0.f, 0.f, 0.f, 0.f};
      f4 st1 = {0.f, 0.f, 0.f, 0.f};
      #pragma unroll
      for (int kk = 0; kk < 4; kk++) {
        s8 bq = *reinterpret_cast<const s8*>(lq + swz(ms * 16 + c16, kk * 64 + quad * 16));
        st0 = mfma16(ak[0][kk], bq, st0);        // one LDS read, two MFMAs
        st1 = mfma16(ak[1][kk], bq, st1);
      }
      #pragma unroll
      for (int r = 0; r < 4; r++) {
        sum0[r] += exp2f(st0[r] * CS);
        sum1[r] += exp2f(st1[r] * CS);
      }
    }
  }
  #pragma unroll
  for (int mask = 1; mask < 16; mask <<= 1) {
    #pragma unroll
    for (int r = 0; r < 4; r++) {
      sum0[r] += __shfl_xor(sum0[r], mask, 64);
      sum1[r] += __shfl_xor(sum1[r], mask, 64);
    }
  }
  if (c16 == 0) {
    float* dst = invb + (long)b * N_ + nb;
    #pragma unroll
    for (int r = 0; r < 4; r++) {
      atomicAdd(dst + quad * 4 + r, sum0[r]);
      atomicAdd(dst + 16 + quad * 4 + r, sum1[r]);
    }
  }
}

// Pass 2a v17 = v13-exact body (94.5us best single measurement; setprio
// dropped — null-to-slightly-negative in r10/r13) + l2ic computed in-kernel:
// prologue fills LI[nslice] = -log2f(invb[n]) in LDS (8KB; write-once, first
// read after the loop's first lds_barrier which drains prologue ds_writes).
// Removes the recip_k launch. LDS 40KB; still 2 blocks/CU (VGPR-bound).
// NO-SPILL CHECKPOINT: FETCH ~16.5MB / WRITE ~32.8MB.
__global__ __launch_bounds__(256, 2) void attn_v17(const u16* __restrict__ q,
    const u16* __restrict__ kpv, const u16* __restrict__ vt,
    const float* __restrict__ invb, float* __restrict__ part,
    int lgns, int nslice) {
  __shared__ char LK[16384];
  __shared__ char LP[16384];
  __shared__ float LI[2048];                     // -log2(sum) for block's n-slice
  const int tid = threadIdx.x;
  const int wave = tid >> 6, lane = tid & 63;
  const int l31 = lane & 31, hi = lane >> 5;
  const int bid = blockIdx.x;                    // b x mb(32) x ns
  const int ns = bid & ((1 << lgns) - 1);
  const int mb = (bid >> lgns) & 31;
  const int b = bid >> (lgns + 5);
  const int nt = wave & 1, mth = wave >> 1;      // wave: n-half nt, m-tiles {mth, mth+2}
  const int m_base = mb * 128;
  const int n_begin = ns * nslice;
  const int rsub = lane >> 4, ch = lane & 15;    // staging roles

  const u16* kpb = kpv + (long)b * N_ * D_;
  const u16* vtb = vt + (long)b * (long)D_ * N_;

  // l2ic prologue: nslice <= 2048 guaranteed (lgns >= 3)
  {
    const float* sb = invb + (long)b * N_ + n_begin;
    for (int i = tid; i < nslice; i += 256) LI[i] = -log2f(sb[i]);
  }

  s8 bq[2][8];                                   // Q B-frags: 2 m-tiles x 8 ksteps
  #pragma unroll
  for (int t = 0; t < 2; t++) {
    const u16* qr = q + ((long)b * M_ + m_base + (mth + 2 * t) * 32 + l31) * D_ + hi * 8;
    #pragma unroll
    for (int kk = 0; kk < 8; kk++) bq[t][kk] = ld8(qr + kk * 16);
  }
  f16v acc[4];                                   // O: 4 m-tiles x wave's 32 d
  #pragma unroll
  for (int i = 0; i < 4; i++)
    #pragma unroll
    for (int r = 0; r < 16; r++) acc[i][r] = 0.f;

  // preload first KPV chunk into regs (v10 staging verbatim)
  s8 tmp[4];
  #pragma unroll
  for (int i = 0; i < 4; i++)
    tmp[i] = ld8(kpb + (long)(n_begin + wave * 16 + i * 4 + rsub) * D_ + ch * 8);

  for (int n0 = n_begin; n0 < n_begin + nslice; n0 += 64) {
    // write staged KPV(i) -> LK
    #pragma unroll
    for (int i = 0; i < 4; i++)
      *reinterpret_cast<s8*>(LK + swz(wave * 16 + i * 4 + rsub, ch * 16)) = tmp[i];
    // prefetch KPV(i+1)
    {
      int nn = n0 + 64;
      if (nn >= n_begin + nslice) nn = n_begin;  // last iter: dummy (unused)
      #pragma unroll
      for (int i = 0; i < 4; i++)
        tmp[i] = ld8(kpb + (long)(nn + wave * 16 + i * 4 + rsub) * D_ + ch * 8);
    }
    lds_barrier();                               // LK+LI ready; LP(PV i-1) done
    // bv hoisted here: lands under the S^T phase (256-VGPR cap, no spill)
    s8 bv[4];
    #pragma unroll
    for (int kk = 0; kk < 4; kk++)
      bv[kk] = ld8(vtb + (long)(wave * 32 + l31) * N_ + n0 + kk * 16 + hi * 8);
    // ---- S^T: two 32n x 32m tiles (shared aK), K=128 ----
    {
      f16v st0, st1;
      #pragma unroll
      for (int r = 0; r < 16; r++) { st0[r] = 0.f; st1[r] = 0.f; }
      #pragma unroll
      for (int kk = 0; kk < 8; kk++) {
        s8 aK = *reinterpret_cast<const s8*>(
            LK + swz(nt * 32 + l31, kk * 32 + hi * 16));
        st0 = mfma32(aK, bq[0][kk], st0);
        st1 = mfma32(aK, bq[1][kk], st1);
      }
      // C: col=m (l31), row n = nt*32 + 8g + 4hi + r  (reg = g*4+r)
      #pragma unroll
      for (int g = 0; g < 4; g++) {
        const f4 l2 = *reinterpret_cast<const f4*>(
            LI + (n0 - n_begin) + nt * 32 + 8 * g + 4 * hi);
        us4 pk0, pk1;
        #pragma unroll
        for (int r = 0; r < 4; r++) {
          pk0[r] = (u16)(__float_as_uint(exp2f(fmaf(st0[g * 4 + r], CS, l2[r]))) >> 16);
          pk1[r] = (u16)(__float_as_uint(exp2f(fmaf(st1[g * 4 + r], CS, l2[r]))) >> 16);
        }
        // LP: granule (4nt+g)*2048, row m in [0,128), byte 8*hi
        *reinterpret_cast<us4*>(LP + (4 * nt + g) * 2048
                                + ((mth + 0) * 32 + l31) * 16 + 8 * hi) = pk0;
        *reinterpret_cast<us4*>(LP + (4 * nt + g) * 2048
                                + ((mth + 2) * 32 + l31) * 16 + 8 * hi) = pk1;
      }
    }
    lds_barrier();                               // LP ready; LK reads done
    // ---- PV: wave owns 32 d (wave*32), 4 m-tiles, K=64 ----
    #pragma unroll
    for (int kk = 0; kk < 4; kk++) {
      #pragma unroll
      for (int i = 0; i < 4; i++) {
        s8 ap = *reinterpret_cast<const s8*>(
            LP + (2 * kk + hi) * 2048 + (i * 32 + l31) * 16);
        acc[i] = mfma32(ap, bv[kk], acc[i]);
      }
    }
  }
  // store partial tile [128m][128d] f32; C: col=d, row m=(reg&3)+8*(reg>>2)+4*hi
  float* pt = part + (long)bid * 128 * 128;
  #pragma unroll
  for (int i = 0; i < 4; i++)
    #pragma unroll
    for (int g = 0; g < 4; g++)
      #pragma unroll
      for (int r = 0; r < 4; r++)
        pt[(i * 32 + g * 8 + 4 * hi + r) * 128 + wave * 32 + l31] = acc[i][g * 4 + r];
}

// Pass 2b: out = sum_ns partial + vfeat  (f32 out). Partials: 128m x 128d tiles.
__global__ __launch_bounds__(256) void attn_reduce(const float* __restrict__ part,
    const float* __restrict__ vfeat, float* __restrict__ out, int nsplit) {
  const int g4 = blockIdx.x * 256 + threadIdx.x;     // 0 .. B*M*D/4-1
  const int b = g4 >> 17;                            // M*D/4 = 131072
  const int rem = g4 & 131071;
  const int m = rem >> 5;
  const int d4 = rem & 31;
  const int mb = m >> 7, mr = m & 127;
  const long base = ((long)(b * 32 + mb) * nsplit) * 16384 + mr * 128 + d4 * 4;
  f4 s = *reinterpret_cast<const f4*>(vfeat + (long)g4 * 4);
  for (int ns = 0; ns < nsplit; ns++)
    s += *reinterpret_cast<const f4*>(part + base + ns * 16384);
  *reinterpret_cast<f4*>(out + (long)g4 * 4) = s;
}

extern "C" void kernel_launch(void* const* d_in, const int* in_sizes, int n_in,
                              void* d_out, int out_size, void* d_ws, size_t ws_size,
                              hipStream_t stream) {
  const float* p_xyz  = (const float*)d_in[0];
  const float* v_xyz  = (const float*)d_in[1];
  const float* p_feat = (const float*)d_in[2];
  const float* v_feat = (const float*)d_in[3];
  const float* aW1 = (const float*)d_in[4],  *ab1 = (const float*)d_in[5];
  const float* aW2 = (const float*)d_in[6],  *ab2 = (const float*)d_in[7];
  const float* bW1 = (const float*)d_in[8],  *bb1 = (const float*)d_in[9];
  const float* bW2 = (const float*)d_in[10], *bb2 = (const float*)d_in[11];
  const float* oW1 = (const float*)d_in[12], *ob1 = (const float*)d_in[13];
  const float* oW2 = (const float*)d_in[14], *ob2 = (const float*)d_in[15];
  const float* dW1 = (const float*)d_in[16], *db1 = (const float*)d_in[17];
  const float* dW2 = (const float*)d_in[18], *db2 = (const float*)d_in[19];

  char* ws = (char*)d_ws;
  u16* wt    = (u16*)ws;                               // 7 * 16384 bf16 elems
  u16* aW1t  = wt + 0 * 16384;
  u16* aW2t  = wt + 1 * 16384;
  u16* bW1t  = wt + 2 * 16384;
  u16* bW2t  = wt + 3 * 16384;
  u16* oW1t  = wt + 4 * 16384;
  u16* oW2t  = wt + 5 * 16384;
  u16* dW2t  = wt + 6 * 16384;
  u16* qbuf  = (u16*)(ws + 262144);                    // B*M*D bf16 = 2 MB
  u16* kpvb  = (u16*)(ws + 2359296);                   // B*N*D bf16 = 8 MB
  u16* vtb   = (u16*)(ws + 10747904);                  // Vt = 8 MB
  float* invb = (float*)(ws + 19136512);               // B*N f32 = 128 KB (exp-sums)
  float* partb = (float*)(ws + 19267584);              // nsplit * 4 MB

  const size_t part_off = 19267584;
  int lgns = (ws_size >= part_off + (size_t)8 * B_ * M_ * D_ * 4) ? 3 : 2;
  const int nsplit = 1 << lgns;                        // capped at 8 (16 null: r9)
  const int nslice = N_ / nsplit;

  hipMemsetAsync(invb, 0, (size_t)B_ * N_ * sizeof(float), stream);
  wtrans<<<dim3(112), dim3(256), 0, stream>>>(aW1, aW2, bW1, bW2, oW1, oW2, dW2, wt);
  mlps<<<dim3(256 + (B_ * N_) / 64), dim3(256), 0, stream>>>(
      v_feat, aW1t, ab1, aW2t, ab2, qbuf,
      p_feat, p_xyz, v_xyz, bW1t, bb1, bW2t, bb2, dW1, db1, dW2t, db2,
      oW1t, ob1, oW2t, ob2, kpvb, vtb);
  colsum_v5<<<dim3(B_ * 64 * 4), dim3(512), 0, stream>>>(qbuf, kpvb, invb);
  attn_v17<<<dim3(B_ * 32 * nsplit), dim3(256), 0, stream>>>(qbuf, kpvb, vtb, invb,
                                                             partb, lgns, nslice);
  attn_reduce<<<dim3((B_ * M_ * D_ / 4) / 256), dim3(256), 0, stream>>>(partb, v_feat,
                                                                        (float*)d_out,
                                                                        nsplit);
}

// Round 15
// 291.922 us; speedup vs baseline: 1.0079x; 1.0079x over previous
//
#include <hip/hip_runtime.h>

#define B_ 2
#define N_ 16384
#define M_ 4096
#define D_ 128

typedef __attribute__((ext_vector_type(8))) short s8;     // 8 bf16 (4 VGPRs)
typedef __attribute__((ext_vector_type(4))) float f4;     // MFMA C/D + float4 loads
typedef __attribute__((ext_vector_type(16))) float f16v;  // 32x32 MFMA C/D
typedef __attribute__((ext_vector_type(4))) unsigned short us4;
typedef unsigned short u16;

__device__ __forceinline__ u16 f2b(float f) {   // RNE float->bf16
  unsigned int x = __float_as_uint(f);
  unsigned int r = x + 0x7fffu + ((x >> 16) & 1u);
  return (u16)(r >> 16);
}
__device__ __forceinline__ s8 ld8(const u16* p) {
  return *reinterpret_cast<const s8*>(p);
}
__device__ __forceinline__ s8 ldcvt8(const float* p) {
  f4 x = *reinterpret_cast<const f4*>(p);
  f4 y = *reinterpret_cast<const f4*>(p + 4);
  s8 r;
  r[0] = (short)f2b(x[0]); r[1] = (short)f2b(x[1]);
  r[2] = (short)f2b(x[2]); r[3] = (short)f2b(x[3]);
  r[4] = (short)f2b(y[0]); r[5] = (short)f2b(y[1]);
  r[6] = (short)f2b(y[2]); r[7] = (short)f2b(y[3]);
  return r;
}
__device__ __forceinline__ f4 mfma16(s8 a, s8 b, f4 c) {
  return __builtin_amdgcn_mfma_f32_16x16x32_bf16(a, b, c, 0, 0, 0);
}
__device__ __forceinline__ f16v mfma32(s8 a, s8 b, f16v c) {
  return __builtin_amdgcn_mfma_f32_32x32x16_bf16(a, b, c, 0, 0, 0);
}
// XOR-swizzled LDS offset for 256B rows. off = byte offset in row.
__device__ __forceinline__ int swz(int row, int off) {
  return (row << 8) + ((((off >> 4) ^ (row & 15)) << 4) | (off & 15));
}
// scale * log2(e): exp(s/sqrt(128)) == exp2(s * CS)
#define CS 0.1275174365f

// LDS-visibility-only barrier: drains ds ops (lgkm) but NOT vmem (vmcnt) —
// v10 verified correctness + parity vs __syncthreads. No sched_barrier pins.
__device__ __forceinline__ void lds_barrier() {
  asm volatile("s_waitcnt lgkmcnt(0)" ::: "memory");
  __builtin_amdgcn_s_barrier();
}

// Transpose seven 128x128 f32 weight matrices into ws as bf16 Wt[n][k].
// 112 blocks: block (mat, part) writes output slice part*1024..+1023 coalesced.
__global__ __launch_bounds__(256) void wtrans(
    const float* a0, const float* a1, const float* a2, const float* a3,
    const float* a4, const float* a5, const float* a6, u16* dst) {
  const int mat = blockIdx.x >> 4, part = blockIdx.x & 15;
  const float* s;
  switch (mat) {
    case 0: s = a0; break; case 1: s = a1; break; case 2: s = a2; break;
    case 3: s = a3; break; case 4: s = a4; break; case 5: s = a5; break;
    default: s = a6; break;
  }
  u16* d = dst + mat * 16384 + part * 1024;
  const int o0 = part * 1024;
  for (int i = threadIdx.x; i < 1024; i += 256) {
    const int o = o0 + i;
    const int c = o >> 7, r = o & 127;
    d[i] = f2b(s[r * 128 + c]);
  }
}

// Fused MLPs, one launch (r12 bodies unchanged):
//  blocks [0,256):   Q = alpha-MLP(v_feat)            -> qbuf
//  blocks [256,768): kpv = beta+delta MLPs, vt = omega -> kpvb / vtb
__global__ __launch_bounds__(256) void mlps(
    const float* __restrict__ vfeat,
    const u16* __restrict__ aW1t, const float* __restrict__ ab1,
    const u16* __restrict__ aW2t, const float* __restrict__ ab2,
    u16* __restrict__ qbuf,
    const float* __restrict__ pf, const float* __restrict__ pxyz,
    const float* __restrict__ vxyz,
    const u16* __restrict__ bW1t, const float* __restrict__ bb1,
    const u16* __restrict__ bW2t, const float* __restrict__ bb2,
    const float* __restrict__ dW1, const float* __restrict__ db1,
    const u16* __restrict__ dW2t, const float* __restrict__ db2,
    const u16* __restrict__ oW1t, const float* __restrict__ ob1,
    const u16* __restrict__ oW2t, const float* __restrict__ ob2,
    u16* __restrict__ kpv_out, u16* __restrict__ vt_out) {
  __shared__ u16 H1[64][136];
  __shared__ u16 H2[64][136];
  __shared__ u16 H3[64][136];
  const int tid = threadIdx.x;
  const int wave = tid >> 6, lane = tid & 63;
  const int c16 = lane & 15, quad = lane >> 4;

  if (blockIdx.x < 256) {
    // ---------------- Q path: 32 rows/block ----------------
    const int rowg = wave & 1, nsh = wave >> 1;
    const long row0 = (long)blockIdx.x * 32 + rowg * 16;
    s8 a[4];
    {
      const float* xr = vfeat + (row0 + c16) * D_ + quad * 8;
      #pragma unroll
      for (int kk = 0; kk < 4; kk++) a[kk] = ldcvt8(xr + kk * 32);
    }
    #pragma unroll
    for (int ns = 0; ns < 4; ns++) {
      f4 acc = {0.f, 0.f, 0.f, 0.f};
      const int c = (nsh * 4 + ns) * 16 + c16;
      const u16* wr = aW1t + (long)c * 128 + quad * 8;
      #pragma unroll
      for (int kk = 0; kk < 4; kk++) acc = mfma16(a[kk], ld8(wr + kk * 32), acc);
      const float bias = ab1[c];
      #pragma unroll
      for (int r = 0; r < 4; r++) {
        float v = acc[r] + bias;
        H1[rowg * 16 + quad * 4 + r][c] = f2b(v > 0.f ? v : 0.f);
      }
    }
    __syncthreads();
    s8 a2[4];
    #pragma unroll
    for (int kk = 0; kk < 4; kk++)
      a2[kk] = *reinterpret_cast<const s8*>(&H1[rowg * 16 + c16][kk * 32 + quad * 8]);
    #pragma unroll
    for (int ns = 0; ns < 4; ns++) {
      f4 acc = {0.f, 0.f, 0.f, 0.f};
      const int c = (nsh * 4 + ns) * 16 + c16;
      const u16* wr = aW2t + (long)c * 128 + quad * 8;
      #pragma unroll
      for (int kk = 0; kk < 4; kk++) acc = mfma16(a2[kk], ld8(wr + kk * 32), acc);
      const float bias = ab2[c];
      #pragma unroll
      for (int r = 0; r < 4; r++)
        qbuf[(row0 + quad * 4 + r) * D_ + c] = f2b(acc[r] + bias);
    }
    return;
  }
  // ---------------- kpv + vt path: 64 rows/block ----------------
  const int bx = blockIdx.x - 256;
  const long row0 = (long)bx * 64 + wave * 16;
  s8 a[4];
  {
    const float* xr = pf + (row0 + c16) * D_ + quad * 8;
    #pragma unroll
    for (int kk = 0; kk < 4; kk++) a[kk] = ldcvt8(xr + kk * 32);
  }
  #pragma unroll
  for (int ns = 0; ns < 8; ns++) {
    f4 accb = {0.f, 0.f, 0.f, 0.f}, acco = {0.f, 0.f, 0.f, 0.f};
    const int c = ns * 16 + c16;
    const u16* wrb = bW1t + (long)c * 128 + quad * 8;
    const u16* wro = oW1t + (long)c * 128 + quad * 8;
    #pragma unroll
    for (int kk = 0; kk < 4; kk++) {
      accb = mfma16(a[kk], ld8(wrb + kk * 32), accb);
      acco = mfma16(a[kk], ld8(wro + kk * 32), acco);
    }
    const float biasb = bb1[c], biaso = ob1[c];
    #pragma unroll
    for (int r = 0; r < 4; r++) {
      float vb = accb[r] + biasb;
      float vo = acco[r] + biaso;
      H1[wave * 16 + quad * 4 + r][c] = f2b(vb > 0.f ? vb : 0.f);
      H3[wave * 16 + quad * 4 + r][c] = f2b(vo > 0.f ? vo : 0.f);
    }
  }
  {
    const long bat = ((long)bx * 64) / N_;
    const float vx0 = vxyz[bat * 3 + 0];
    const float vx1 = vxyz[bat * 3 + 1];
    const float vx2 = vxyz[bat * 3 + 2];
    for (int i = 0; i < 32; i++) {
      const int e = lane + 64 * i;
      const int rr = e >> 7, cc = e & 127;
      const long gr = row0 + rr;
      const float d0 = fabsf(pxyz[gr * 3 + 0] - vx0);
      const float d1 = fabsf(pxyz[gr * 3 + 1] - vx1);
      const float d2 = fabsf(pxyz[gr * 3 + 2] - vx2);
      float h = d0 * dW1[cc] + d1 * dW1[128 + cc] + d2 * dW1[256 + cc] + db1[cc];
      H2[wave * 16 + rr][cc] = f2b(h > 0.f ? h : 0.f);
    }
  }
  __syncthreads();                               // single fence: writes -> reads
  s8 ab[4], ad[4], ao[4];
  #pragma unroll
  for (int kk = 0; kk < 4; kk++) {
    ab[kk] = *reinterpret_cast<const s8*>(&H1[wave * 16 + c16][kk * 32 + quad * 8]);
    ad[kk] = *reinterpret_cast<const s8*>(&H2[wave * 16 + c16][kk * 32 + quad * 8]);
    ao[kk] = *reinterpret_cast<const s8*>(&H3[wave * 16 + c16][kk * 32 + quad * 8]);
  }
  #pragma unroll
  for (int ns = 0; ns < 8; ns++) {
    const int c = ns * 16 + c16;
    f4 acck = {0.f, 0.f, 0.f, 0.f};              // kpv = beta-L2 + delta-L2
    f4 accv = {0.f, 0.f, 0.f, 0.f};              // vt = omega-L2
    const u16* wrb = bW2t + (long)c * 128 + quad * 8;
    const u16* wrd = dW2t + (long)c * 128 + quad * 8;
    const u16* wro = oW2t + (long)c * 128 + quad * 8;
    #pragma unroll
    for (int kk = 0; kk < 4; kk++) {
      acck = mfma16(ab[kk], ld8(wrb + kk * 32), acck);
      acck = mfma16(ad[kk], ld8(wrd + kk * 32), acck);
      accv = mfma16(ao[kk], ld8(wro + kk * 32), accv);
    }
    const float biask = bb2[c] + db2[c];
    const float biasv = ob2[c];
    #pragma unroll
    for (int r = 0; r < 4; r++)
      kpv_out[(row0 + quad * 4 + r) * D_ + c] = f2b(acck[r] + biask);
    {
      const long g = row0 + quad * 4;
      const long bb = g >> 14;
      const long n = g & (N_ - 1);
      us4 pk;
      #pragma unroll
      for (int r = 0; r < 4; r++) pk[r] = f2b(accv[r] + biasv);
      *reinterpret_cast<us4*>(vt_out + bb * (long)128 * N_ + (long)c * N_ + n) = pk;
    }
  }
}

// Pass 1 v5 (r14 verified: out of top-5, no spill): A-register reuse, atomics
// into invb (zeroed by hipMemsetAsync), no separate recip pass.
__global__ __launch_bounds__(512, 2) void colsum_v5(const u16* __restrict__ q,
    const u16* __restrict__ kpv, float* __restrict__ invb) {
  __shared__ char LQ[2][32768];                  // 2 x (128 m x 128 k bf16), swz
  const int tid = threadIdx.x;
  const int wave = tid >> 6, lane = tid & 63;
  const int c16 = lane & 15, quad = lane >> 4;
  const int mh = blockIdx.x & 3;                 // m-split
  const int nblk = (blockIdx.x >> 2) & 63;       // 256-n block
  const int b = blockIdx.x >> 8;
  const int nb = nblk * 256 + wave * 32;         // wave's 32 n rows
  const int rsub = lane >> 4, ch = lane & 15;

  s8 ak[2][4];                                   // two 16-n A-tiles
  #pragma unroll
  for (int t = 0; t < 2; t++) {
    const u16* kr = kpv + ((long)b * N_ + nb + t * 16 + c16) * D_ + quad * 8;
    #pragma unroll
    for (int kk = 0; kk < 4; kk++) ak[t][kk] = ld8(kr + kk * 32);
  }
  f4 sum0 = {0.f, 0.f, 0.f, 0.f};
  f4 sum1 = {0.f, 0.f, 0.f, 0.f};
  const u16* qb = q + (long)b * M_ * D_ + (long)mh * (M_ / 4) * D_;

  // prologue: stage 0 (load + write)
  {
    s8 t4[4];
    #pragma unroll
    for (int i = 0; i < 4; i++)
      t4[i] = ld8(qb + (long)(wave * 16 + i * 4 + rsub) * D_ + ch * 8);
    #pragma unroll
    for (int i = 0; i < 4; i++)
      *reinterpret_cast<s8*>(LQ[0] + swz(wave * 16 + i * 4 + rsub, ch * 16)) = t4[i];
  }

  for (int s = 0; s < 8; s++) {                  // 8 stages x 128 m = M/4
    lds_barrier();                               // W(s) visible; R(s-1) done
    if (s < 7) {                                 // stage s+1: load+write now
      s8 t4[4];                                  // (short liveness: no spill)
      const int m1 = (s + 1) * 128;
      #pragma unroll
      for (int i = 0; i < 4; i++)
        t4[i] = ld8(qb + (long)(m1 + wave * 16 + i * 4 + rsub) * D_ + ch * 8);
      #pragma unroll
      for (int i = 0; i < 4; i++)
        *reinterpret_cast<s8*>(LQ[(s + 1) & 1]
            + swz(wave * 16 + i * 4 + rsub, ch * 16)) = t4[i];
    }
    const char* lq = LQ[s & 1];
    #pragma unroll
    for (int ms = 0; ms < 8; ms++) {
      f4 st0 = {0.f, 0.f, 0.f, 0.f};
      f4 st1 = {0.f, 0.f, 0.f, 0.f};
      #pragma unroll
      for (int kk = 0; kk < 4; kk++) {
        s8 bq = *reinterpret_cast<const s8*>(lq + swz(ms * 16 + c16, kk * 64 + quad * 16));
        st0 = mfma16(ak[0][kk], bq, st0);        // one LDS read, two MFMAs
        st1 = mfma16(ak[1][kk], bq, st1);
      }
      #pragma unroll
      for (int r = 0; r < 4; r++) {
        sum0[r] += exp2f(st0[r] * CS);
        sum1[r] += exp2f(st1[r] * CS);
      }
    }
  }
  #pragma unroll
  for (int mask = 1; mask < 16; mask <<= 1) {
    #pragma unroll
    for (int r = 0; r < 4; r++) {
      sum0[r] += __shfl_xor(sum0[r], mask, 64);
      sum1[r] += __shfl_xor(sum1[r], mask, 64);
    }
  }
  if (c16 == 0) {
    float* dst = invb + (long)b * N_ + nb;
    #pragma unroll
    for (int r = 0; r < 4; r++) {
      atomicAdd(dst + quad * 4 + r, sum0[r]);
      atomicAdd(dst + 16 + quad * 4 + r, sum1[r]);
    }
  }
}

// Pass 2a v18: v13's overhead-per-FLOP lever applied ONE MORE NOTCH.
// m-tile 128 -> 256 with a 512-thread (8-wave) block; per-wave resources are
// IDENTICAL to v13/v17 (bq[2][8]=64 + acc[4]=64 VGPR, 2 S^T tiles + 4 PV
// m-tiles per wave). Per 64n iteration: same 2 barriers, same 16 staged rows
// (8 waves x 8 rows), same LK tile — amortized over 2x the MFMAs. KPV
// staging re-reads per batch halve (16 mb-blocks vs 32) -> FETCH ~16.5->~13MB.
// Grid B*16*nsplit = 256 @ nsplit=8 -> 1 block/CU x 8 waves = same 8 waves/CU
// as v13 (v15: wave-count invariance). LDS 16(LK)+32(LP)+16(LI) = 64KB.
// __launch_bounds__(512,2): 256-VGPR budget (no v9/v12 spill trap).
// NO-SPILL CHECKPOINT: FETCH must not inflate past ~20MB, WRITE ~32.8MB.
__global__ __launch_bounds__(512, 2) void attn_v18(const u16* __restrict__ q,
    const u16* __restrict__ kpv, const u16* __restrict__ vt,
    const float* __restrict__ invb, float* __restrict__ part,
    int lgns, int nslice) {
  __shared__ char LK[16384];                     // 64n x 128k bf16, swz
  __shared__ char LP[32768];                     // 8 granules x [256m][8n] bf16
  __shared__ float LI[4096];                     // -log2(sum), block's n-slice
  const int tid = threadIdx.x;
  const int wave = tid >> 6, lane = tid & 63;
  const int l31 = lane & 31, hi = lane >> 5;
  const int bid = blockIdx.x;                    // b x mb(16) x ns
  const int ns = bid & ((1 << lgns) - 1);
  const int mb = (bid >> lgns) & 15;
  const int b = bid >> (lgns + 4);
  const int nt = wave & 1, mth = wave >> 1;      // S^T: n-half nt, m-tiles {mth, mth+4}
  const int dsl = wave >> 1, mhalf = wave & 1;   // PV: d-slice dsl*32, m-tiles mhalf*4..+3
  const int m_base = mb * 256;
  const int n_begin = ns * nslice;
  const int rsub = lane >> 4, ch = lane & 15;    // staging roles (8 rows/wave)

  const u16* kpb = kpv + (long)b * N_ * D_;
  const u16* vtb = vt + (long)b * (long)D_ * N_;

  // l2ic prologue (nslice <= 4096)
  {
    const float* sb = invb + (long)b * N_ + n_begin;
    for (int i = tid; i < nslice; i += 512) LI[i] = -log2f(sb[i]);
  }

  s8 bq[2][8];                                   // Q B-frags: 2 m-tiles x 8 ksteps
  #pragma unroll
  for (int t = 0; t < 2; t++) {
    const u16* qr = q + ((long)b * M_ + m_base + (mth + 4 * t) * 32 + l31) * D_ + hi * 8;
    #pragma unroll
    for (int kk = 0; kk < 8; kk++) bq[t][kk] = ld8(qr + kk * 16);
  }
  f16v acc[4];                                   // O: 4 m-tiles x wave's 32 d
  #pragma unroll
  for (int i = 0; i < 4; i++)
    #pragma unroll
    for (int r = 0; r < 16; r++) acc[i][r] = 0.f;

  // preload first KPV chunk into regs (8 rows/wave = 2 passes of 4)
  s8 tmp[2];
  #pragma unroll
  for (int p = 0; p < 2; p++)
    tmp[p] = ld8(kpb + (long)(n_begin + wave * 8 + p * 4 + rsub) * D_ + ch * 8);

  for (int n0 = n_begin; n0 < n_begin + nslice; n0 += 64) {
    // write staged KPV(i) -> LK
    #pragma unroll
    for (int p = 0; p < 2; p++)
      *reinterpret_cast<s8*>(LK + swz(wave * 8 + p * 4 + rsub, ch * 16)) = tmp[p];
    // prefetch KPV(i+1)
    {
      int nn = n0 + 64;
      if (nn >= n_begin + nslice) nn = n_begin;  // last iter: dummy (unused)
      #pragma unroll
      for (int p = 0; p < 2; p++)
        tmp[p] = ld8(kpb + (long)(nn + wave * 8 + p * 4 + rsub) * D_ + ch * 8);
    }
    lds_barrier();                               // LK+LI ready; LP(PV i-1) done
    // bv for this iter's PV (2 waves share each d-slice; L1 broadcast)
    s8 bv[4];
    #pragma unroll
    for (int kk = 0; kk < 4; kk++)
      bv[kk] = ld8(vtb + (long)(dsl * 32 + l31) * N_ + n0 + kk * 16 + hi * 8);
    // ---- S^T: two 32n x 32m tiles (shared aK), K=128 ----
    {
      f16v st0, st1;
      #pragma unroll
      for (int r = 0; r < 16; r++) { st0[r] = 0.f; st1[r] = 0.f; }
      #pragma unroll
      for (int kk = 0; kk < 8; kk++) {
        s8 aK = *reinterpret_cast<const s8*>(
            LK + swz(nt * 32 + l31, kk * 32 + hi * 16));
        st0 = mfma32(aK, bq[0][kk], st0);
        st1 = mfma32(aK, bq[1][kk], st1);
      }
      // C: col=m (l31), row n = nt*32 + 8g + 4hi + r  (reg = g*4+r)
      #pragma unroll
      for (int g = 0; g < 4; g++) {
        const f4 l2 = *reinterpret_cast<const f4*>(
            LI + (n0 - n_begin) + nt * 32 + 8 * g + 4 * hi);
        us4 pk0, pk1;
        #pragma unroll
        for (int r = 0; r < 4; r++) {
          pk0[r] = (u16)(__float_as_uint(exp2f(fmaf(st0[g * 4 + r], CS, l2[r]))) >> 16);
          pk1[r] = (u16)(__float_as_uint(exp2f(fmaf(st1[g * 4 + r], CS, l2[r]))) >> 16);
        }
        // LP: granule (4nt+g)*4096, row m in [0,256), byte 8*hi
        *reinterpret_cast<us4*>(LP + (4 * nt + g) * 4096
                                + ((mth + 0) * 32 + l31) * 16 + 8 * hi) = pk0;
        *reinterpret_cast<us4*>(LP + (4 * nt + g) * 4096
                                + ((mth + 4) * 32 + l31) * 16 + 8 * hi) = pk1;
      }
    }
    lds_barrier();                               // LP ready; LK reads done
    // ---- PV: wave owns 32 d (dsl*32), m-tiles mhalf*4..+3, K=64 ----
    #pragma unroll
    for (int kk = 0; kk < 4; kk++) {
      #pragma unroll
      for (int i = 0; i < 4; i++) {
        s8 ap = *reinterpret_cast<const s8*>(
            LP + (2 * kk + hi) * 4096 + ((mhalf * 4 + i) * 32 + l31) * 16);
        acc[i] = mfma32(ap, bv[kk], acc[i]);
      }
    }
  }
  // store partial tile [256m][128d] f32; C: col=d, row m=(reg&3)+8*(reg>>2)+4*hi
  float* pt = part + (long)bid * 256 * 128;
  #pragma unroll
  for (int i = 0; i < 4; i++)
    #pragma unroll
    for (int g = 0; g < 4; g++)
      #pragma unroll
      for (int r = 0; r < 4; r++)
        pt[((mhalf * 4 + i) * 32 + g * 8 + 4 * hi + r) * 128 + dsl * 32 + l31]
            = acc[i][g * 4 + r];
}

// Pass 2b: out = sum_ns partial + vfeat  (f32 out). Partials: 256m x 128d tiles.
__global__ __launch_bounds__(256) void attn_reduce(const float* __restrict__ part,
    const float* __restrict__ vfeat, float* __restrict__ out, int nsplit) {
  const int g4 = blockIdx.x * 256 + threadIdx.x;     // 0 .. B*M*D/4-1
  const int b = g4 >> 17;                            // M*D/4 = 131072
  const int rem = g4 & 131071;
  const int m = rem >> 5;
  const int d4 = rem & 31;
  const int mb = m >> 8, mr = m & 255;
  const long base = ((long)(b * 16 + mb) * nsplit) * 32768 + mr * 128 + d4 * 4;
  f4 s = *reinterpret_cast<const f4*>(vfeat + (long)g4 * 4);
  for (int ns = 0; ns < nsplit; ns++)
    s += *reinterpret_cast<const f4*>(part + base + ns * 32768);
  *reinterpret_cast<f4*>(out + (long)g4 * 4) = s;
}

extern "C" void kernel_launch(void* const* d_in, const int* in_sizes, int n_in,
                              void* d_out, int out_size, void* d_ws, size_t ws_size,
                              hipStream_t stream) {
  const float* p_xyz  = (const float*)d_in[0];
  const float* v_xyz  = (const float*)d_in[1];
  const float* p_feat = (const float*)d_in[2];
  const float* v_feat = (const float*)d_in[3];
  const float* aW1 = (const float*)d_in[4],  *ab1 = (const float*)d_in[5];
  const float* aW2 = (const float*)d_in[6],  *ab2 = (const float*)d_in[7];
  const float* bW1 = (const float*)d_in[8],  *bb1 = (const float*)d_in[9];
  const float* bW2 = (const float*)d_in[10], *bb2 = (const float*)d_in[11];
  const float* oW1 = (const float*)d_in[12], *ob1 = (const float*)d_in[13];
  const float* oW2 = (const float*)d_in[14], *ob2 = (const float*)d_in[15];
  const float* dW1 = (const float*)d_in[16], *db1 = (const float*)d_in[17];
  const float* dW2 = (const float*)d_in[18], *db2 = (const float*)d_in[19];

  char* ws = (char*)d_ws;
  u16* wt    = (u16*)ws;                               // 7 * 16384 bf16 elems
  u16* aW1t  = wt + 0 * 16384;
  u16* aW2t  = wt + 1 * 16384;
  u16* bW1t  = wt + 2 * 16384;
  u16* bW2t  = wt + 3 * 16384;
  u16* oW1t  = wt + 4 * 16384;
  u16* oW2t  = wt + 5 * 16384;
  u16* dW2t  = wt + 6 * 16384;
  u16* qbuf  = (u16*)(ws + 262144);                    // B*M*D bf16 = 2 MB
  u16* kpvb  = (u16*)(ws + 2359296);                   // B*N*D bf16 = 8 MB
  u16* vtb   = (u16*)(ws + 10747904);                  // Vt = 8 MB
  float* invb = (float*)(ws + 19136512);               // B*N f32 = 128 KB (exp-sums)
  float* partb = (float*)(ws + 19267584);              // nsplit * 4 MB

  const size_t part_off = 19267584;
  int lgns = (ws_size >= part_off + (size_t)8 * B_ * M_ * D_ * 4) ? 3 : 2;
  const int nsplit = 1 << lgns;                        // 8 -> 256 blocks = 1/CU
  const int nslice = N_ / nsplit;

  hipMemsetAsync(invb, 0, (size_t)B_ * N_ * sizeof(float), stream);
  wtrans<<<dim3(112), dim3(256), 0, stream>>>(aW1, aW2, bW1, bW2, oW1, oW2, dW2, wt);
  mlps<<<dim3(256 + (B_ * N_) / 64), dim3(256), 0, stream>>>(
      v_feat, aW1t, ab1, aW2t, ab2, qbuf,
      p_feat, p_xyz, v_xyz, bW1t, bb1, bW2t, bb2, dW1, db1, dW2t, db2,
      oW1t, ob1, oW2t, ob2, kpvb, vtb);
  colsum_v5<<<dim3(B_ * 64 * 4), dim3(512), 0, stream>>>(qbuf, kpvb, invb);
  attn_v18<<<dim3(B_ * 16 * nsplit), dim3(512), 0, stream>>>(qbuf, kpvb, vtb, invb,
                                                             partb, lgns, nslice);
  attn_reduce<<<dim3((B_ * M_ * D_ / 4) / 256), dim3(256), 0, stream>>>(partb, v_feat,
                                                                        (float*)d_out,
                                                                        nsplit);
}